// Round 1
// baseline (635.331 us; speedup 1.0000x reference)
//
#include <hip/hip_runtime.h>
#include <stdint.h>

#define BB 16
#define SS 2048
#define FF 512
#define DD 128
#define CC 1000

typedef __attribute__((ext_vector_type(8))) short bf16x8;
typedef __attribute__((ext_vector_type(4))) float f32x4;

__device__ __forceinline__ unsigned short f2bf(float f) {
  unsigned x;
  __builtin_memcpy(&x, &f, 4);
  x = x + 0x7FFFu + ((x >> 16) & 1u);
  return (unsigned short)(x >> 16);
}
__device__ __forceinline__ float bf2f(unsigned short u) {
  unsigned x = ((unsigned)u) << 16;
  float f;
  __builtin_memcpy(&f, &x, 4);
  return f;
}
__device__ __forceinline__ unsigned pk2(float a, float b) {
  return (unsigned)f2bf(a) | ((unsigned)f2bf(b) << 16);
}

// ---- workspace layout (bytes) ----
#define WS_WG   256        // float wg[16][2048]
#define WS_ZG   131328     // float zg[16][2048]
#define WS_YG   262400     // float yg[16][128]
#define WS_PK   270592     // packed mask bits uint32 [B][S][64] (8 MB)
#define WS_Q    8659200    // bf16 [B][S][128], q pre-scaled by D^-0.5
#define WS_K    17047808
#define WS_V    25436416
#define WS_WT   33825024   // bf16 WT[3][128][512]
#define WS_END  34218240
// optional P buffer: bf16 [B][S][S] = 128 MiB (only used when ws_size permits)
#define WS_P    34218240
#define WS_END2 168435968

// ---------------- probe mask dtype + zero accumulators ----------------
__global__ __launch_bounds__(256) void k_detect(const unsigned* __restrict__ mask,
                                                int* __restrict__ flags,
                                                float* __restrict__ wgl,
                                                float* __restrict__ zgl,
                                                float* __restrict__ ygl) {
  __shared__ unsigned red;
  const int tid = threadIdx.x;
  if (tid == 0) red = 0;
  __syncthreads();
  unsigned a = 0;
#pragma unroll
  for (int j = 0; j < 4; ++j) a |= mask[tid * 4 + j] & 0xFFFFFF00u;
  if (a) atomicOr(&red, 1u);
  __syncthreads();
  if (tid == 0) flags[0] = (red == 0) ? 1 : 0;   // 1 = int32 mask, 0 = byte
  for (int i = tid; i < BB * SS; i += 256) { wgl[i] = 0.f; zgl[i] = 0.f; }
  for (int i = tid; i < BB * DD; i += 256) ygl[i] = 0.f;
}

// ---------------- pack mask (0/1) into bitmask ----------------
__global__ __launch_bounds__(256) void k_pack(const void* __restrict__ mask,
                                              const int* __restrict__ flags,
                                              unsigned* __restrict__ pk) {
  const int tid = threadIdx.x;
  const long long base = (long long)blockIdx.x * 2048;
  const bool isInt = flags[0] != 0;
#pragma unroll
  for (int it = 0; it < 8; ++it) {
    long long e = base + it * 256 + tid;
    int val;
    if (isInt) val = ((const int*)mask)[e];
    else       val = ((const unsigned char*)mask)[e];
    unsigned long long bal = __ballot(val != 0);
    if ((tid & 31) == 0)
      pk[e >> 5] = (unsigned)((tid & 63) ? (bal >> 32) : bal);
  }
}

// ---------------- transpose+convert Wq/Wk/Wv fp32[512][128] -> bf16 WT[3][128][512] --
__global__ __launch_bounds__(256) void k_wt(const float* __restrict__ Wq,
                                            const float* __restrict__ Wk,
                                            const float* __restrict__ Wv,
                                            unsigned short* __restrict__ wt) {
  int idx = blockIdx.x * 256 + threadIdx.x;
  int ty = idx >> 16;
  int o = idx & 65535;
  int d = o >> 9, f = o & 511;
  const float* W = ty == 0 ? Wq : (ty == 1 ? Wk : Wv);
  wt[idx] = f2bf(W[f * DD + d]);
}

// ---------------- QKV projection ----------------
__global__ __launch_bounds__(256) void k_proj(const float* __restrict__ xg,
                                              const unsigned short* __restrict__ wtg,
                                              const float* __restrict__ bq,
                                              const float* __restrict__ bk,
                                              const float* __restrict__ bv,
                                              unsigned short* __restrict__ qo,
                                              unsigned short* __restrict__ ko,
                                              unsigned short* __restrict__ vo) {
  __shared__ __align__(16) char lA[8192];
  __shared__ __align__(16) char lB[8192];
  const int tid = threadIdx.x;
  const int lane = tid & 63;
  const int wv = tid >> 6;
  const int colL = lane & 15, quad = lane >> 4;
  const int blk = blockIdx.x, ty = blockIdx.y;
  const float* bias = ty == 0 ? bq : (ty == 1 ? bk : bv);
  unsigned short* outp = ty == 0 ? qo : (ty == 1 ? ko : vo);
  const float scale = ty == 0 ? 0.08838834764831845f : 1.0f;
  const unsigned short* wbase = wtg + (size_t)ty * 65536;
  const int m0 = (wv & 1) * 64, n0 = (wv >> 1) * 64;

  f32x4 acc[4][4];
  const f32x4 z4 = {0.f, 0.f, 0.f, 0.f};
#pragma unroll
  for (int mi = 0; mi < 4; ++mi)
#pragma unroll
    for (int ni = 0; ni < 4; ++ni) acc[mi][ni] = z4;

  for (int ic = 0; ic < 16; ++ic) {
    const int k0 = ic * 32;
    uint4 va[2], vb[2];
#pragma unroll
    for (int rr = 0; rr < 2; ++rr) {
      int p = rr * 256 + tid;
      int row = p >> 2, c = p & 3;
      const float* xp = xg + (size_t)(blk * 128 + row) * FF + k0 + c * 8;
      float4 x0 = *(const float4*)xp;
      float4 x1 = *(const float4*)(xp + 4);
      va[rr].x = pk2(x0.x, x0.y); va[rr].y = pk2(x0.z, x0.w);
      va[rr].z = pk2(x1.x, x1.y); va[rr].w = pk2(x1.z, x1.w);
      vb[rr] = *(const uint4*)(wbase + (size_t)row * FF + k0 + c * 8);
    }
    __syncthreads();
#pragma unroll
    for (int rr = 0; rr < 2; ++rr) {
      int p = rr * 256 + tid;
      int row = p >> 2, c = p & 3;
      int phys = c ^ ((row >> 1) & 3);
      *(uint4*)(lA + row * 64 + phys * 16) = va[rr];
      *(uint4*)(lB + row * 64 + phys * 16) = vb[rr];
    }
    __syncthreads();
    bf16x8 af[4], bfr[4];
#pragma unroll
    for (int mi = 0; mi < 4; ++mi) {
      int ar = m0 + mi * 16 + colL;
      int phys = quad ^ ((ar >> 1) & 3);
      af[mi] = *(const bf16x8*)(lA + ar * 64 + phys * 16);
    }
#pragma unroll
    for (int ni = 0; ni < 4; ++ni) {
      int br = n0 + ni * 16 + colL;
      int phys = quad ^ ((br >> 1) & 3);
      bfr[ni] = *(const bf16x8*)(lB + br * 64 + phys * 16);
    }
#pragma unroll
    for (int mi = 0; mi < 4; ++mi)
#pragma unroll
      for (int ni = 0; ni < 4; ++ni)
        acc[mi][ni] = __builtin_amdgcn_mfma_f32_16x16x32_bf16(af[mi], bfr[ni], acc[mi][ni], 0, 0, 0);
  }
#pragma unroll
  for (int ni = 0; ni < 4; ++ni) {
    int col = n0 + ni * 16 + colL;
    float bval = bias[col];
#pragma unroll
    for (int mi = 0; mi < 4; ++mi) {
#pragma unroll
      for (int r = 0; r < 4; ++r) {
        int row = blk * 128 + m0 + mi * 16 + quad * 4 + r;
        float val = (acc[mi][ni][r] + bval) * scale;
        outp[(size_t)row * DD + col] = f2bf(val);
      }
    }
  }
}

// ---------------- attention over (sb, tc, b) ----------------
// MODE 0: accumulate Z[b][s] partials (no P store)      [fallback pass 1]
// MODE 1: accumulate Z partials AND store P=exp as bf16 [primary pass 1]
// MODE 2: recompute exp, colsum exp/Z -> wg[b][t]       [fallback pass 2]
// Per block: 128 q-rows x 256 t-cols (4 k-tiles of 64). LDS ~22 KB.
template <int MODE>
__global__ __launch_bounds__(256) void k_attn2(const unsigned short* __restrict__ qg,
                                               const unsigned short* __restrict__ kg,
                                               const unsigned* __restrict__ pk,
                                               float* __restrict__ zg,
                                               float* __restrict__ wg,
                                               unsigned short* __restrict__ pg) {
  __shared__ __align__(16) char kt[16384];   // 64 rows x 256B, chunk swizzle c^(r&7)
  __shared__ unsigned maskt[128 * 9];        // stride 9 words -> quad offsets hit distinct banks
  __shared__ float wacc[256];
  const int tid = threadIdx.x;
  const int lane = tid & 63, wv = tid >> 6;
  const int colL = lane & 15, quad = lane >> 4;
  const int row0 = blockIdx.x * 128;
  const int tc = blockIdx.y;                 // 8 chunks of 256 t
  const int b = blockIdx.z;
  const int tbase = tc * 256;

  // stage mask words for rows x t-chunk
  for (int i = tid; i < 1024; i += 256) {
    int row = i >> 3, w = i & 7;
    maskt[row * 9 + w] = pk[((size_t)b * SS + row0 + row) * 64 + tc * 8 + w];
  }
  if (MODE == 2) wacc[tid] = 0.f;

  bf16x8 qf[2][4];
#pragma unroll
  for (int mi = 0; mi < 2; ++mi) {
    int qrow = row0 + wv * 32 + mi * 16 + colL;   // A-frag m = colL
    const unsigned short* qp = qg + ((size_t)b * SS + qrow) * DD + quad * 8;
#pragma unroll
    for (int kk = 0; kk < 4; ++kk) qf[mi][kk] = *(const bf16x8*)(qp + kk * 32);
  }
  float z[2][4] = {{0.f, 0.f, 0.f, 0.f}, {0.f, 0.f, 0.f, 0.f}};
  float zinv[2][4];
  if (MODE == 2) {
#pragma unroll
    for (int mi = 0; mi < 2; ++mi)
#pragma unroll
      for (int r = 0; r < 4; ++r) {
        int row = row0 + wv * 32 + mi * 16 + quad * 4 + r;
        zinv[mi][r] = 1.0f / fmaxf(zg[(size_t)b * SS + row], 1e-30f);
      }
  }

  for (int kt0 = 0; kt0 < 4; ++kt0) {
    const int t0 = tbase + kt0 * 64;
    uint4 kreg[4];
#pragma unroll
    for (int rr = 0; rr < 4; ++rr) {
      int p = rr * 256 + tid;
      int row = p >> 4, c = p & 15;
      kreg[rr] = *(const uint4*)(kg + ((size_t)b * SS + t0 + row) * DD + c * 8);
    }
    __syncthreads();   // maskt/wacc staged (it0); previous tile reads done (it>0)
#pragma unroll
    for (int rr = 0; rr < 4; ++rr) {
      int p = rr * 256 + tid;
      int row = p >> 4, c = p & 15;
      int phys = c ^ (row & 7);
      *(uint4*)(kt + row * 256 + phys * 16) = kreg[rr];
    }
    __syncthreads();
#pragma unroll
    for (int nt = 0; nt < 4; ++nt) {
      int rb = nt * 16 + colL;
      bf16x8 bb[4];
#pragma unroll
      for (int kk = 0; kk < 4; ++kk) {
        int phys = (kk * 4 + quad) ^ (rb & 7);
        bb[kk] = *(const bf16x8*)(kt + rb * 256 + phys * 16);
      }
      int tl = kt0 * 64 + nt * 16 + colL;      // local t in 0..255
      int wl = tl >> 5, wb = tl & 31;
      float cs = 0.f;
#pragma unroll
      for (int mi = 0; mi < 2; ++mi) {
        f32x4 acc = {0.f, 0.f, 0.f, 0.f};
        acc = __builtin_amdgcn_mfma_f32_16x16x32_bf16(qf[mi][0], bb[0], acc, 0, 0, 0);
        acc = __builtin_amdgcn_mfma_f32_16x16x32_bf16(qf[mi][1], bb[1], acc, 0, 0, 0);
        acc = __builtin_amdgcn_mfma_f32_16x16x32_bf16(qf[mi][2], bb[2], acc, 0, 0, 0);
        acc = __builtin_amdgcn_mfma_f32_16x16x32_bf16(qf[mi][3], bb[3], acc, 0, 0, 0);
        int rbase = wv * 32 + mi * 16 + quad * 4;
        unsigned short* pp;
        if (MODE == 1)
          pp = pg + ((size_t)b * SS + row0 + rbase) * SS + tbase + tl;
#pragma unroll
        for (int r = 0; r < 4; ++r) {
          unsigned mw = maskt[(rbase + r) * 9 + wl];
          float e = ((mw >> wb) & 1u) ? 0.f : __expf(fminf(acc[r], 80.f));
          if (MODE != 2) z[mi][r] += e;
          else cs += e * zinv[mi][r];
          if (MODE == 1) pp[(size_t)r * SS] = f2bf(e);
        }
      }
      if (MODE == 2) {
        cs += __shfl_xor(cs, 16, 64);
        cs += __shfl_xor(cs, 32, 64);
        if (quad == 0) atomicAdd(&wacc[tl], cs);
      }
    }
  }
  if (MODE != 2) {
#pragma unroll
    for (int mi = 0; mi < 2; ++mi)
#pragma unroll
      for (int r = 0; r < 4; ++r) {
        float s = z[mi][r];
        s += __shfl_xor(s, 1, 64);
        s += __shfl_xor(s, 2, 64);
        s += __shfl_xor(s, 4, 64);
        s += __shfl_xor(s, 8, 64);
        if (colL == 0) {
          int row = row0 + wv * 32 + mi * 16 + quad * 4 + r;
          atomicAdd(&zg[(size_t)b * SS + row], s);
        }
      }
  } else {
    __syncthreads();
    atomicAdd(&wg[(size_t)b * SS + tbase + tid], wacc[tid]);
  }
}

// ---------------- primary pass 2: wg[b][t] = sum_s P[b][s][t] / Z[b][s] ----------------
// Pure stream over P (128 MiB). Grid (32 s-chunks of 64, B). Thread owns 8 t-cols.
__global__ __launch_bounds__(256) void k_csum(const unsigned short* __restrict__ pg,
                                              const float* __restrict__ zg,
                                              float* __restrict__ wg) {
  __shared__ float zl[64];
  const int tid = threadIdx.x;
  const int s0 = blockIdx.x * 64;
  const int b = blockIdx.y;
  if (tid < 64) zl[tid] = 1.0f / fmaxf(zg[(size_t)b * SS + s0 + tid], 1e-30f);
  __syncthreads();
  float acc[8] = {0.f, 0.f, 0.f, 0.f, 0.f, 0.f, 0.f, 0.f};
  const unsigned short* base = pg + ((size_t)b * SS + s0) * SS + tid * 8;
#pragma unroll 4
  for (int s = 0; s < 64; ++s) {
    bf16x8 pv = *(const bf16x8*)(base + (size_t)s * SS);
    float zi = zl[s];
#pragma unroll
    for (int j = 0; j < 8; ++j) acc[j] += bf2f((unsigned short)pv[j]) * zi;
  }
  float* wrow = wg + (size_t)b * SS + tid * 8;
#pragma unroll
  for (int j = 0; j < 8; ++j) atomicAdd(&wrow[j], acc[j]);
}

// ---------------- y partials: y[b][d] = sum_t wg[b][t] * V[b][t][d] ----------------
__global__ __launch_bounds__(256) void k_yv(const float* __restrict__ wgl,
                                            const unsigned short* __restrict__ vg,
                                            float* __restrict__ ygl) {
  const int tid = threadIdx.x;
  const int tc = blockIdx.x, b = blockIdx.y;
  const int d = tid & 127, half = tid >> 7;
  const int t0 = tc * 128 + half * 64;
  float p = 0.f;
  const float* wrow = wgl + (size_t)b * SS + t0;
  const unsigned short* vrow = vg + ((size_t)b * SS + t0) * DD + d;
#pragma unroll 8
  for (int t = 0; t < 64; ++t) p += wrow[t] * bf2f(vrow[(size_t)t * DD]);
  atomicAdd(&ygl[b * DD + d], p);
}

// ---------------- out = (y/S) @ Wl + bl  (fp32 out) ----------------
__global__ __launch_bounds__(256) void k_out(const float* __restrict__ ygl,
                                             const float* __restrict__ Wl,
                                             const float* __restrict__ bl,
                                             float* __restrict__ outp) {
  __shared__ float ys[DD];
  const int tid = threadIdx.x;
  const int b = blockIdx.x;
  if (tid < DD) ys[tid] = ygl[b * DD + tid] * (1.0f / 2048.0f);
  __syncthreads();
  for (int c = tid; c < CC; c += 256) {
    float a = bl[c];
#pragma unroll 16
    for (int dd = 0; dd < DD; ++dd) a += ys[dd] * Wl[dd * CC + c];
    outp[b * CC + c] = a;
  }
}

extern "C" void kernel_launch(void* const* d_in, const int* in_sizes, int n_in,
                              void* d_out, int out_size, void* d_ws, size_t ws_size,
                              hipStream_t stream) {
  const void* ptr[10];
  for (int i = 0; i < 10; ++i) ptr[i] = (i < n_in) ? d_in[i] : nullptr;
  if (n_in == 10) {  // size-based slot matching (no-op under dict order)
    const void *px = 0, *pm = 0, *pWl = 0, *pbl = 0;
    const void* pW[3] = {0, 0, 0};
    const void* pb[3] = {0, 0, 0};
    int nW = 0, nb = 0;
    for (int i = 0; i < 10; ++i) {
      int s = in_sizes[i];
      if (s == 16777216) px = d_in[i];
      else if (s == 67108864) pm = d_in[i];
      else if (s == 128000) pWl = d_in[i];
      else if (s == 1000) pbl = d_in[i];
      else if (s == 65536 && nW < 3) pW[nW++] = d_in[i];
      else if (s == 128 && nb < 3) pb[nb++] = d_in[i];
    }
    if (px && pm && pWl && pbl && nW == 3 && nb == 3) {
      ptr[0] = px; ptr[1] = pm;
      ptr[2] = pW[0]; ptr[3] = pb[0];
      ptr[4] = pW[1]; ptr[5] = pb[1];
      ptr[6] = pW[2]; ptr[7] = pb[2];
      ptr[8] = pWl; ptr[9] = pbl;
    }
  }
  char* ws = (char*)d_ws;
  if (ws_size < (size_t)WS_END) return;
  int* flags = (int*)ws;
  float* wg = (float*)(ws + WS_WG);
  float* zg = (float*)(ws + WS_ZG);
  float* yg = (float*)(ws + WS_YG);
  unsigned* pk = (unsigned*)(ws + WS_PK);
  unsigned short* q  = (unsigned short*)(ws + WS_Q);
  unsigned short* k  = (unsigned short*)(ws + WS_K);
  unsigned short* v  = (unsigned short*)(ws + WS_V);
  unsigned short* wt = (unsigned short*)(ws + WS_WT);
  unsigned short* pbuf = (unsigned short*)(ws + WS_P);
  const bool bigws = ws_size >= (size_t)WS_END2;

  k_detect<<<1, 256, 0, stream>>>((const unsigned*)ptr[1], flags, wg, zg, yg);
  k_pack<<<32768, 256, 0, stream>>>(ptr[1], flags, pk);
  k_wt<<<768, 256, 0, stream>>>((const float*)ptr[2], (const float*)ptr[4],
                                (const float*)ptr[6], wt);
  k_proj<<<dim3(256, 3), 256, 0, stream>>>((const float*)ptr[0], wt,
                                           (const float*)ptr[3], (const float*)ptr[5],
                                           (const float*)ptr[7], q, k, v);
  if (bigws) {
    k_attn2<1><<<dim3(16, 8, 16), 256, 0, stream>>>(q, k, pk, zg, wg, pbuf);
    k_csum<<<dim3(32, 16), 256, 0, stream>>>(pbuf, zg, wg);
  } else {
    k_attn2<0><<<dim3(16, 8, 16), 256, 0, stream>>>(q, k, pk, zg, wg, nullptr);
    k_attn2<2><<<dim3(16, 8, 16), 256, 0, stream>>>(q, k, pk, zg, wg, nullptr);
  }
  k_yv<<<dim3(16, 16), 256, 0, stream>>>(wg, v, yg);
  k_out<<<16, 256, 0, stream>>>(yg, (const float*)ptr[8], (const float*)ptr[9],
                                (float*)d_out);
}

// Round 2
// 621.307 us; speedup vs baseline: 1.0226x; 1.0226x over previous
//
#include <hip/hip_runtime.h>
#include <stdint.h>

#define BB 16
#define SS 2048
#define FF 512
#define DD 128
#define CC 1000

typedef __attribute__((ext_vector_type(8))) short bf16x8;
typedef __attribute__((ext_vector_type(4))) float f32x4;

__device__ __forceinline__ unsigned short f2bf(float f) {
  unsigned x;
  __builtin_memcpy(&x, &f, 4);
  x = x + 0x7FFFu + ((x >> 16) & 1u);
  return (unsigned short)(x >> 16);
}
__device__ __forceinline__ float bf2f(unsigned short u) {
  unsigned x = ((unsigned)u) << 16;
  float f;
  __builtin_memcpy(&f, &x, 4);
  return f;
}
__device__ __forceinline__ unsigned pk2(float a, float b) {
  return (unsigned)f2bf(a) | ((unsigned)f2bf(b) << 16);
}

// ---- workspace layout (bytes) ----
#define WS_WG   256        // float wg[16][2048]
#define WS_ZG   131328     // float zg[16][2048]
#define WS_YG   262400     // float yg[16][128]
#define WS_PK   270592     // packed mask bits uint32 [B][S][64] (8 MB)
#define WS_Q    8659200    // bf16 [B][S][128], q pre-scaled by D^-0.5
#define WS_K    17047808
#define WS_V    25436416
#define WS_WT   33825024   // bf16 WT[3][128][512]
#define WS_END  34218240
// optional P buffer: bf16 [B][S][S] = 128 MiB (only used when ws_size permits)
#define WS_P    34218240
#define WS_END2 168435968

// ---------------- Wq/Wk/Wv transpose+convert; block 768 = mask-dtype probe + zeroing --
__global__ __launch_bounds__(256) void k_wt(const float* __restrict__ Wq,
                                            const float* __restrict__ Wk,
                                            const float* __restrict__ Wv,
                                            unsigned short* __restrict__ wt,
                                            const unsigned* __restrict__ mask,
                                            int* __restrict__ flags,
                                            float* __restrict__ wgl,
                                            float* __restrict__ zgl,
                                            float* __restrict__ ygl) {
  const int tid = threadIdx.x;
  if (blockIdx.x == 768) {   // detect + zero accumulators
    __shared__ unsigned red;
    if (tid == 0) red = 0;
    __syncthreads();
    unsigned a = 0;
#pragma unroll
    for (int j = 0; j < 4; ++j) a |= mask[tid * 4 + j] & 0xFFFFFF00u;
    if (a) atomicOr(&red, 1u);
    __syncthreads();
    if (tid == 0) flags[0] = (red == 0) ? 1 : 0;   // 1 = int32 mask, 0 = byte
    for (int i = tid; i < BB * SS; i += 256) { wgl[i] = 0.f; zgl[i] = 0.f; }
    for (int i = tid; i < BB * DD; i += 256) ygl[i] = 0.f;
    return;
  }
  int idx = blockIdx.x * 256 + tid;
  int ty = idx >> 16;
  int o = idx & 65535;
  int d = o >> 9, f = o & 511;
  const float* W = ty == 0 ? Wq : (ty == 1 ? Wk : Wv);
  wt[idx] = f2bf(W[f * DD + d]);
}

// ---------------- pack mask (0/1) into bitmask ----------------
__global__ __launch_bounds__(256) void k_pack(const void* __restrict__ mask,
                                              const int* __restrict__ flags,
                                              unsigned* __restrict__ pk) {
  const int tid = threadIdx.x;
  const long long base = (long long)blockIdx.x * 32768;
  const bool isInt = flags[0] != 0;
  for (int it = 0; it < 128; ++it) {
    long long e = base + it * 256 + tid;
    int val;
    if (isInt) val = ((const int*)mask)[e];
    else       val = ((const unsigned char*)mask)[e];
    unsigned long long bal = __ballot(val != 0);
    if ((tid & 31) == 0)
      pk[e >> 5] = (unsigned)((tid & 63) ? (bal >> 32) : bal);
  }
}

// ---------------- QKV projection ----------------
__global__ __launch_bounds__(256) void k_proj(const float* __restrict__ xg,
                                              const unsigned short* __restrict__ wtg,
                                              const float* __restrict__ bq,
                                              const float* __restrict__ bk,
                                              const float* __restrict__ bv,
                                              unsigned short* __restrict__ qo,
                                              unsigned short* __restrict__ ko,
                                              unsigned short* __restrict__ vo) {
  __shared__ __align__(16) char lA[8192];
  __shared__ __align__(16) char lB[8192];
  const int tid = threadIdx.x;
  const int lane = tid & 63;
  const int wv = tid >> 6;
  const int colL = lane & 15, quad = lane >> 4;
  const int blk = blockIdx.x, ty = blockIdx.y;
  const float* bias = ty == 0 ? bq : (ty == 1 ? bk : bv);
  unsigned short* outp = ty == 0 ? qo : (ty == 1 ? ko : vo);
  const float scale = ty == 0 ? 0.08838834764831845f : 1.0f;
  const unsigned short* wbase = wtg + (size_t)ty * 65536;
  const int m0 = (wv & 1) * 64, n0 = (wv >> 1) * 64;

  f32x4 acc[4][4];
  const f32x4 z4 = {0.f, 0.f, 0.f, 0.f};
#pragma unroll
  for (int mi = 0; mi < 4; ++mi)
#pragma unroll
    for (int ni = 0; ni < 4; ++ni) acc[mi][ni] = z4;

  for (int ic = 0; ic < 16; ++ic) {
    const int k0 = ic * 32;
    uint4 va[2], vb[2];
#pragma unroll
    for (int rr = 0; rr < 2; ++rr) {
      int p = rr * 256 + tid;
      int row = p >> 2, c = p & 3;
      const float* xp = xg + (size_t)(blk * 128 + row) * FF + k0 + c * 8;
      float4 x0 = *(const float4*)xp;
      float4 x1 = *(const float4*)(xp + 4);
      va[rr].x = pk2(x0.x, x0.y); va[rr].y = pk2(x0.z, x0.w);
      va[rr].z = pk2(x1.x, x1.y); va[rr].w = pk2(x1.z, x1.w);
      vb[rr] = *(const uint4*)(wbase + (size_t)row * FF + k0 + c * 8);
    }
    __syncthreads();
#pragma unroll
    for (int rr = 0; rr < 2; ++rr) {
      int p = rr * 256 + tid;
      int row = p >> 2, c = p & 3;
      int phys = c ^ ((row >> 1) & 3);
      *(uint4*)(lA + row * 64 + phys * 16) = va[rr];
      *(uint4*)(lB + row * 64 + phys * 16) = vb[rr];
    }
    __syncthreads();
    bf16x8 af[4], bfr[4];
#pragma unroll
    for (int mi = 0; mi < 4; ++mi) {
      int ar = m0 + mi * 16 + colL;
      int phys = quad ^ ((ar >> 1) & 3);
      af[mi] = *(const bf16x8*)(lA + ar * 64 + phys * 16);
    }
#pragma unroll
    for (int ni = 0; ni < 4; ++ni) {
      int br = n0 + ni * 16 + colL;
      int phys = quad ^ ((br >> 1) & 3);
      bfr[ni] = *(const bf16x8*)(lB + br * 64 + phys * 16);
    }
#pragma unroll
    for (int mi = 0; mi < 4; ++mi)
#pragma unroll
      for (int ni = 0; ni < 4; ++ni)
        acc[mi][ni] = __builtin_amdgcn_mfma_f32_16x16x32_bf16(af[mi], bfr[ni], acc[mi][ni], 0, 0, 0);
  }
#pragma unroll
  for (int ni = 0; ni < 4; ++ni) {
    int col = n0 + ni * 16 + colL;
    float bval = bias[col];
#pragma unroll
    for (int mi = 0; mi < 4; ++mi) {
#pragma unroll
      for (int r = 0; r < 4; ++r) {
        int row = blk * 128 + m0 + mi * 16 + quad * 4 + r;
        float val = (acc[mi][ni][r] + bval) * scale;
        outp[(size_t)row * DD + col] = f2bf(val);
      }
    }
  }
}

// ---------------- attention over (sb, tc, b) ----------------
// MODE 0: accumulate Z[b][s] partials (no P store)      [fallback pass 1]
// MODE 1: accumulate Z partials AND store P=exp as bf16 [primary pass 1]
//         P tile staged in LDS, written coalesced (16B/lane, 128B segments)
// MODE 2: recompute exp, colsum exp/Z -> wg[b][t]       [fallback pass 2]
template <int MODE>
__global__ __launch_bounds__(256) void k_attn2(const unsigned short* __restrict__ qg,
                                               const unsigned short* __restrict__ kg,
                                               const unsigned* __restrict__ pk,
                                               float* __restrict__ zg,
                                               float* __restrict__ wg,
                                               unsigned short* __restrict__ pg) {
  __shared__ __align__(16) char kt[16384];   // 64 rows x 256B, chunk swizzle c^(r&7)
  __shared__ unsigned maskt[128 * 9];        // stride 9 words -> quad offsets hit distinct banks
  __shared__ float wacc[256];                // MODE 2 only (DCE'd otherwise)
  __shared__ __align__(16) unsigned short pt[128 * 64];  // MODE 1 only: P tile 16 KB
  const int tid = threadIdx.x;
  const int lane = tid & 63, wv = tid >> 6;
  const int colL = lane & 15, quad = lane >> 4;
  const int row0 = blockIdx.x * 128;
  const int tc = blockIdx.y;                 // 8 chunks of 256 t
  const int b = blockIdx.z;
  const int tbase = tc * 256;

  // stage mask words for rows x t-chunk
  for (int i = tid; i < 1024; i += 256) {
    int row = i >> 3, w = i & 7;
    maskt[row * 9 + w] = pk[((size_t)b * SS + row0 + row) * 64 + tc * 8 + w];
  }
  if constexpr (MODE == 2) wacc[tid] = 0.f;

  bf16x8 qf[2][4];
#pragma unroll
  for (int mi = 0; mi < 2; ++mi) {
    int qrow = row0 + wv * 32 + mi * 16 + colL;   // A-frag m = colL
    const unsigned short* qp = qg + ((size_t)b * SS + qrow) * DD + quad * 8;
#pragma unroll
    for (int kk = 0; kk < 4; ++kk) qf[mi][kk] = *(const bf16x8*)(qp + kk * 32);
  }
  float z[2][4] = {{0.f, 0.f, 0.f, 0.f}, {0.f, 0.f, 0.f, 0.f}};
  float zinv[2][4];
  if constexpr (MODE == 2) {
#pragma unroll
    for (int mi = 0; mi < 2; ++mi)
#pragma unroll
      for (int r = 0; r < 4; ++r) {
        int row = row0 + wv * 32 + mi * 16 + quad * 4 + r;
        zinv[mi][r] = 1.0f / fmaxf(zg[(size_t)b * SS + row], 1e-30f);
      }
  }

  for (int kt0 = 0; kt0 < 4; ++kt0) {
    const int t0 = tbase + kt0 * 64;
    uint4 kreg[4];
#pragma unroll
    for (int rr = 0; rr < 4; ++rr) {
      int p = rr * 256 + tid;
      int row = p >> 4, c = p & 15;
      kreg[rr] = *(const uint4*)(kg + ((size_t)b * SS + t0 + row) * DD + c * 8);
    }
    __syncthreads();   // maskt staged (it0); previous tile LDS reads done (it>0)
#pragma unroll
    for (int rr = 0; rr < 4; ++rr) {
      int p = rr * 256 + tid;
      int row = p >> 4, c = p & 15;
      int phys = c ^ (row & 7);
      *(uint4*)(kt + row * 256 + phys * 16) = kreg[rr];
    }
    __syncthreads();
#pragma unroll
    for (int nt = 0; nt < 4; ++nt) {
      int rb = nt * 16 + colL;
      bf16x8 bb[4];
#pragma unroll
      for (int kk = 0; kk < 4; ++kk) {
        int phys = (kk * 4 + quad) ^ (rb & 7);
        bb[kk] = *(const bf16x8*)(kt + rb * 256 + phys * 16);
      }
      int tl = kt0 * 64 + nt * 16 + colL;      // local t in 0..255
      int ct = nt * 16 + colL;                 // col within kt0 tile, 0..63
      int wl = tl >> 5, wb = tl & 31;
      float cs = 0.f;
#pragma unroll
      for (int mi = 0; mi < 2; ++mi) {
        f32x4 acc = {0.f, 0.f, 0.f, 0.f};
        acc = __builtin_amdgcn_mfma_f32_16x16x32_bf16(qf[mi][0], bb[0], acc, 0, 0, 0);
        acc = __builtin_amdgcn_mfma_f32_16x16x32_bf16(qf[mi][1], bb[1], acc, 0, 0, 0);
        acc = __builtin_amdgcn_mfma_f32_16x16x32_bf16(qf[mi][2], bb[2], acc, 0, 0, 0);
        acc = __builtin_amdgcn_mfma_f32_16x16x32_bf16(qf[mi][3], bb[3], acc, 0, 0, 0);
        int rbase = wv * 32 + mi * 16 + quad * 4;
#pragma unroll
        for (int r = 0; r < 4; ++r) {
          unsigned mw = maskt[(rbase + r) * 9 + wl];
          float e = ((mw >> wb) & 1u) ? 0.f : __expf(fminf(acc[r], 80.f));
          if constexpr (MODE != 2) z[mi][r] += e;
          else cs += e * zinv[mi][r];
          if constexpr (MODE == 1) {
            int rw = rbase + r;
            pt[rw * 64 + (ct ^ ((rw & 7) << 3))] = f2bf(e);  // 16B-chunk XOR swizzle
          }
        }
      }
      if constexpr (MODE == 2) {
        cs += __shfl_xor(cs, 16, 64);
        cs += __shfl_xor(cs, 32, 64);
        if (quad == 0) atomicAdd(&wacc[tl], cs);
      }
    }
    if constexpr (MODE == 1) {
      __syncthreads();   // pt fully written by all waves
      unsigned short* prow = pg + ((size_t)b * SS + row0) * SS + t0;
#pragma unroll
      for (int i2 = 0; i2 < 4; ++i2) {
        int ii = i2 * 256 + tid;
        int rw = ii >> 3, c8 = ii & 7;
        uint4 vv = *(const uint4*)(pt + rw * 64 + ((c8 ^ (rw & 7)) * 8));
        *(uint4*)(prow + (size_t)rw * SS + c8 * 8) = vv;
      }
      // next iteration's staging barrier orders pt reads before pt rewrites
    }
  }
  if constexpr (MODE != 2) {
#pragma unroll
    for (int mi = 0; mi < 2; ++mi)
#pragma unroll
      for (int r = 0; r < 4; ++r) {
        float s = z[mi][r];
        s += __shfl_xor(s, 1, 64);
        s += __shfl_xor(s, 2, 64);
        s += __shfl_xor(s, 4, 64);
        s += __shfl_xor(s, 8, 64);
        if (colL == 0) {
          int row = row0 + wv * 32 + mi * 16 + quad * 4 + r;
          atomicAdd(&zg[(size_t)b * SS + row], s);
        }
      }
  } else {
    __syncthreads();
    atomicAdd(&wg[(size_t)b * SS + tbase + tid], wacc[tid]);
  }
}

// ---------------- primary pass 2: wg[b][t] = sum_s P[b][s][t] / Z[b][s] ----------------
// Pure stream over P (128 MiB). Grid (8 s-chunks of 256, B). Thread owns 8 t-cols.
__global__ __launch_bounds__(256) void k_csum(const unsigned short* __restrict__ pg,
                                              const float* __restrict__ zg,
                                              float* __restrict__ wg) {
  __shared__ float zl[256];
  const int tid = threadIdx.x;
  const int s0 = blockIdx.x * 256;
  const int b = blockIdx.y;
  zl[tid] = 1.0f / fmaxf(zg[(size_t)b * SS + s0 + tid], 1e-30f);
  __syncthreads();
  float acc[8] = {0.f, 0.f, 0.f, 0.f, 0.f, 0.f, 0.f, 0.f};
  const unsigned short* base = pg + ((size_t)b * SS + s0) * SS + tid * 8;
#pragma unroll 4
  for (int s = 0; s < 256; ++s) {
    bf16x8 pv = *(const bf16x8*)(base + (size_t)s * SS);
    float zi = zl[s];
#pragma unroll
    for (int j = 0; j < 8; ++j) acc[j] += bf2f((unsigned short)pv[j]) * zi;
  }
  float* wrow = wg + (size_t)b * SS + tid * 8;
#pragma unroll
  for (int j = 0; j < 8; ++j) atomicAdd(&wrow[j], acc[j]);
}

// ---------------- y partials: y[b][d] = sum_t wg[b][t] * V[b][t][d] ----------------
__global__ __launch_bounds__(256) void k_yv(const float* __restrict__ wgl,
                                            const unsigned short* __restrict__ vg,
                                            float* __restrict__ ygl) {
  const int tid = threadIdx.x;
  const int tc = blockIdx.x, b = blockIdx.y;
  const int d = tid & 127, half = tid >> 7;
  const int t0 = tc * 128 + half * 64;
  float p = 0.f;
  const float* wrow = wgl + (size_t)b * SS + t0;
  const unsigned short* vrow = vg + ((size_t)b * SS + t0) * DD + d;
#pragma unroll 8
  for (int t = 0; t < 64; ++t) p += wrow[t] * bf2f(vrow[(size_t)t * DD]);
  atomicAdd(&ygl[b * DD + d], p);
}

// ---------------- out = (y/S) @ Wl + bl  (fp32 out) ----------------
__global__ __launch_bounds__(256) void k_out(const float* __restrict__ ygl,
                                             const float* __restrict__ Wl,
                                             const float* __restrict__ bl,
                                             float* __restrict__ outp) {
  __shared__ float ys[DD];
  const int tid = threadIdx.x;
  const int b = blockIdx.x;
  if (tid < DD) ys[tid] = ygl[b * DD + tid] * (1.0f / 2048.0f);
  __syncthreads();
  for (int c = tid; c < CC; c += 256) {
    float a = bl[c];
#pragma unroll 16
    for (int dd = 0; dd < DD; ++dd) a += ys[dd] * Wl[dd * CC + c];
    outp[b * CC + c] = a;
  }
}

extern "C" void kernel_launch(void* const* d_in, const int* in_sizes, int n_in,
                              void* d_out, int out_size, void* d_ws, size_t ws_size,
                              hipStream_t stream) {
  const void* ptr[10];
  for (int i = 0; i < 10; ++i) ptr[i] = (i < n_in) ? d_in[i] : nullptr;
  if (n_in == 10) {  // size-based slot matching (no-op under dict order)
    const void *px = 0, *pm = 0, *pWl = 0, *pbl = 0;
    const void* pW[3] = {0, 0, 0};
    const void* pb[3] = {0, 0, 0};
    int nW = 0, nb = 0;
    for (int i = 0; i < 10; ++i) {
      int s = in_sizes[i];
      if (s == 16777216) px = d_in[i];
      else if (s == 67108864) pm = d_in[i];
      else if (s == 128000) pWl = d_in[i];
      else if (s == 1000) pbl = d_in[i];
      else if (s == 65536 && nW < 3) pW[nW++] = d_in[i];
      else if (s == 128 && nb < 3) pb[nb++] = d_in[i];
    }
    if (px && pm && pWl && pbl && nW == 3 && nb == 3) {
      ptr[0] = px; ptr[1] = pm;
      ptr[2] = pW[0]; ptr[3] = pb[0];
      ptr[4] = pW[1]; ptr[5] = pb[1];
      ptr[6] = pW[2]; ptr[7] = pb[2];
      ptr[8] = pWl; ptr[9] = pbl;
    }
  }
  char* ws = (char*)d_ws;
  if (ws_size < (size_t)WS_END) return;
  int* flags = (int*)ws;
  float* wg = (float*)(ws + WS_WG);
  float* zg = (float*)(ws + WS_ZG);
  float* yg = (float*)(ws + WS_YG);
  unsigned* pk = (unsigned*)(ws + WS_PK);
  unsigned short* q  = (unsigned short*)(ws + WS_Q);
  unsigned short* k  = (unsigned short*)(ws + WS_K);
  unsigned short* v  = (unsigned short*)(ws + WS_V);
  unsigned short* wt = (unsigned short*)(ws + WS_WT);
  unsigned short* pbuf = (unsigned short*)(ws + WS_P);
  const bool bigws = ws_size >= (size_t)WS_END2;

  k_wt<<<769, 256, 0, stream>>>((const float*)ptr[2], (const float*)ptr[4],
                                (const float*)ptr[6], wt,
                                (const unsigned*)ptr[1], flags, wg, zg, yg);
  k_pack<<<2048, 256, 0, stream>>>(ptr[1], flags, pk);
  k_proj<<<dim3(256, 3), 256, 0, stream>>>((const float*)ptr[0], wt,
                                           (const float*)ptr[3], (const float*)ptr[5],
                                           (const float*)ptr[7], q, k, v);
  if (bigws) {
    k_attn2<1><<<dim3(16, 8, 16), 256, 0, stream>>>(q, k, pk, zg, wg, pbuf);
    k_csum<<<dim3(8, 16), 256, 0, stream>>>(pbuf, zg, wg);
  } else {
    k_attn2<0><<<dim3(16, 8, 16), 256, 0, stream>>>(q, k, pk, zg, wg, nullptr);
    k_attn2<2><<<dim3(16, 8, 16), 256, 0, stream>>>(q, k, pk, zg, wg, nullptr);
  }
  k_yv<<<dim3(16, 16), 256, 0, stream>>>(wg, v, yg);
  k_out<<<16, 256, 0, stream>>>(yg, (const float*)ptr[8], (const float*)ptr[9],
                                (float*)d_out);
}

// Round 3
// 610.929 us; speedup vs baseline: 1.0399x; 1.0170x over previous
//
#include <hip/hip_runtime.h>
#include <stdint.h>

#define BB 16
#define SS 2048
#define FF 512
#define DD 128
#define CC 1000

typedef __attribute__((ext_vector_type(8))) short bf16x8;
typedef __attribute__((ext_vector_type(4))) float f32x4;

__device__ __forceinline__ unsigned short f2bf(float f) {
  unsigned x;
  __builtin_memcpy(&x, &f, 4);
  x = x + 0x7FFFu + ((x >> 16) & 1u);
  return (unsigned short)(x >> 16);
}
__device__ __forceinline__ float bf2f(unsigned short u) {
  unsigned x = ((unsigned)u) << 16;
  float f;
  __builtin_memcpy(&f, &x, 4);
  return f;
}
__device__ __forceinline__ unsigned pk2(float a, float b) {
  return (unsigned)f2bf(a) | ((unsigned)f2bf(b) << 16);
}

// ---- workspace layout (bytes) ----
#define WS_WG   256        // float wg[16][2048]
#define WS_ZG   131328     // float zg[16][2048] (zeroed, unused by fused path)
#define WS_YG   262400     // float yg[16][128]
#define WS_PK   270592     // packed mask bits uint32 [B][S][64] (8 MB)
#define WS_Q    8659200    // bf16 [B][S][128], q pre-scaled by D^-0.5
#define WS_K    17047808
#define WS_V    25436416
#define WS_WT   33825024   // bf16 WT[3][128][512]
#define WS_END  34218240

// ---------------- Wq/Wk/Wv transpose+convert; block 768 = mask-dtype probe + zeroing --
__global__ __launch_bounds__(256) void k_wt(const float* __restrict__ Wq,
                                            const float* __restrict__ Wk,
                                            const float* __restrict__ Wv,
                                            unsigned short* __restrict__ wt,
                                            const unsigned* __restrict__ mask,
                                            int* __restrict__ flags,
                                            float* __restrict__ wgl,
                                            float* __restrict__ zgl,
                                            float* __restrict__ ygl) {
  const int tid = threadIdx.x;
  if (blockIdx.x == 768) {   // detect + zero accumulators
    __shared__ unsigned red;
    if (tid == 0) red = 0;
    __syncthreads();
    unsigned a = 0;
#pragma unroll
    for (int j = 0; j < 4; ++j) a |= mask[tid * 4 + j] & 0xFFFFFF00u;
    if (a) atomicOr(&red, 1u);
    __syncthreads();
    if (tid == 0) flags[0] = (red == 0) ? 1 : 0;   // 1 = int32 mask, 0 = byte
    for (int i = tid; i < BB * SS; i += 256) { wgl[i] = 0.f; zgl[i] = 0.f; }
    for (int i = tid; i < BB * DD; i += 256) ygl[i] = 0.f;
    return;
  }
  int idx = blockIdx.x * 256 + tid;
  int ty = idx >> 16;
  int o = idx & 65535;
  int d = o >> 9, f = o & 511;
  const float* W = ty == 0 ? Wq : (ty == 1 ? Wk : Wv);
  wt[idx] = f2bf(W[f * DD + d]);
}

// ---------------- pack mask (0/1) into bitmask ----------------
__global__ __launch_bounds__(256) void k_pack(const void* __restrict__ mask,
                                              const int* __restrict__ flags,
                                              unsigned* __restrict__ pk) {
  const int tid = threadIdx.x;
  const long long base = (long long)blockIdx.x * 32768;
  const bool isInt = flags[0] != 0;
  for (int it = 0; it < 128; ++it) {
    long long e = base + it * 256 + tid;
    int val;
    if (isInt) val = ((const int*)mask)[e];
    else       val = ((const unsigned char*)mask)[e];
    unsigned long long bal = __ballot(val != 0);
    if ((tid & 31) == 0)
      pk[e >> 5] = (unsigned)((tid & 63) ? (bal >> 32) : bal);
  }
}

// ---------------- QKV projection ----------------
__global__ __launch_bounds__(256) void k_proj(const float* __restrict__ xg,
                                              const unsigned short* __restrict__ wtg,
                                              const float* __restrict__ bq,
                                              const float* __restrict__ bk,
                                              const float* __restrict__ bv,
                                              unsigned short* __restrict__ qo,
                                              unsigned short* __restrict__ ko,
                                              unsigned short* __restrict__ vo) {
  __shared__ __align__(16) char lA[8192];
  __shared__ __align__(16) char lB[8192];
  const int tid = threadIdx.x;
  const int lane = tid & 63;
  const int wv = tid >> 6;
  const int colL = lane & 15, quad = lane >> 4;
  const int blk = blockIdx.x, ty = blockIdx.y;
  const float* bias = ty == 0 ? bq : (ty == 1 ? bk : bv);
  unsigned short* outp = ty == 0 ? qo : (ty == 1 ? ko : vo);
  const float scale = ty == 0 ? 0.08838834764831845f : 1.0f;
  const unsigned short* wbase = wtg + (size_t)ty * 65536;
  const int m0 = (wv & 1) * 64, n0 = (wv >> 1) * 64;

  f32x4 acc[4][4];
  const f32x4 z4 = {0.f, 0.f, 0.f, 0.f};
#pragma unroll
  for (int mi = 0; mi < 4; ++mi)
#pragma unroll
    for (int ni = 0; ni < 4; ++ni) acc[mi][ni] = z4;

  for (int ic = 0; ic < 16; ++ic) {
    const int k0 = ic * 32;
    uint4 va[2], vb[2];
#pragma unroll
    for (int rr = 0; rr < 2; ++rr) {
      int p = rr * 256 + tid;
      int row = p >> 2, c = p & 3;
      const float* xp = xg + (size_t)(blk * 128 + row) * FF + k0 + c * 8;
      float4 x0 = *(const float4*)xp;
      float4 x1 = *(const float4*)(xp + 4);
      va[rr].x = pk2(x0.x, x0.y); va[rr].y = pk2(x0.z, x0.w);
      va[rr].z = pk2(x1.x, x1.y); va[rr].w = pk2(x1.z, x1.w);
      vb[rr] = *(const uint4*)(wbase + (size_t)row * FF + k0 + c * 8);
    }
    __syncthreads();
#pragma unroll
    for (int rr = 0; rr < 2; ++rr) {
      int p = rr * 256 + tid;
      int row = p >> 2, c = p & 3;
      int phys = c ^ ((row >> 1) & 3);
      *(uint4*)(lA + row * 64 + phys * 16) = va[rr];
      *(uint4*)(lB + row * 64 + phys * 16) = vb[rr];
    }
    __syncthreads();
    bf16x8 af[4], bfr[4];
#pragma unroll
    for (int mi = 0; mi < 4; ++mi) {
      int ar = m0 + mi * 16 + colL;
      int phys = quad ^ ((ar >> 1) & 3);
      af[mi] = *(const bf16x8*)(lA + ar * 64 + phys * 16);
    }
#pragma unroll
    for (int ni = 0; ni < 4; ++ni) {
      int br = n0 + ni * 16 + colL;
      int phys = quad ^ ((br >> 1) & 3);
      bfr[ni] = *(const bf16x8*)(lB + br * 64 + phys * 16);
    }
#pragma unroll
    for (int mi = 0; mi < 4; ++mi)
#pragma unroll
      for (int ni = 0; ni < 4; ++ni)
        acc[mi][ni] = __builtin_amdgcn_mfma_f32_16x16x32_bf16(af[mi], bfr[ni], acc[mi][ni], 0, 0, 0);
  }
#pragma unroll
  for (int ni = 0; ni < 4; ++ni) {
    int col = n0 + ni * 16 + colL;
    float bval = bias[col];
#pragma unroll
    for (int mi = 0; mi < 4; ++mi) {
#pragma unroll
      for (int r = 0; r < 4; ++r) {
        int row = blk * 128 + m0 + mi * 16 + quad * 4 + r;
        float val = (acc[mi][ni][r] + bval) * scale;
        outp[(size_t)row * DD + col] = f2bf(val);
      }
    }
  }
}

// ---------------- fused attention: P kept entirely in LDS ----------------
// Block = (row-group rg of 32 q-rows, batch b). 512 threads = 8 waves
// (wr = row-half 0..1, wq = t-quarter 0..3). Sweeps all 2048 t in 32
// chunks of 64 (K chunk staged in LDS, reg-double-buffered). P tile
// 32x2048 bf16 = 128 KB LDS (row-XOR swizzle). Z is block-local; after
// the sweep: zinv, then column sums P[r][t]*zinv[r] -> atomicAdd wg.
__global__ __launch_bounds__(512, 2) void k_fatt(const unsigned short* __restrict__ qg,
                                                 const unsigned short* __restrict__ kg,
                                                 const unsigned* __restrict__ pk,
                                                 float* __restrict__ wg) {
  extern __shared__ __align__(16) char smem[];
  unsigned short* pt = (unsigned short*)smem;          // [32][2048] bf16, 131072 B
  char* kt = smem + 131072;                            // [64][256 B] swizzled, 16384 B
  unsigned* mk = (unsigned*)(smem + 147456);           // [32][65] mask words, 8320 B
  float* zfin = (float*)(smem + 155776);               // [32]
  float* zinvl = (float*)(smem + 155904);              // [32]

  const int tid = threadIdx.x;
  const int lane = tid & 63, wv = tid >> 6;
  const int colL = lane & 15, quad = lane >> 4;
  const int wr = wv & 1, wq = wv >> 1;
  const int r0 = blockIdx.x * 32;
  const int b = blockIdx.y;

  // stage mask words: rows r0..r0+31, all 64 words (stride 65 kills quad-bank aliasing)
  for (int i = tid; i < 2048; i += 512) {
    int row = i >> 6, w = i & 63;
    mk[row * 65 + w] = pk[((size_t)b * SS + r0 + row) * 64 + w];
  }
  if (tid < 32) zfin[tid] = 0.f;

  // Q fragments for this wave's 16 rows (A-frag m = colL, proven layout)
  bf16x8 qf[4];
  {
    int qrow = r0 + wr * 16 + colL;
    const unsigned short* qp = qg + ((size_t)b * SS + qrow) * DD + quad * 8;
#pragma unroll
    for (int kk = 0; kk < 4; ++kk) qf[kk] = *(const bf16x8*)(qp + kk * 32);
  }

  // K staging role: thread -> (row 0..63, 16B-chunk pair)
  const int krow = tid >> 3, kc8 = tid & 7;
  const unsigned short* kbase = kg + ((size_t)b * SS + krow) * DD;
  const int kswz0 = (kc8 ^ (krow & 7)) * 16;
  const int kswz1 = ((kc8 + 8) ^ (krow & 7)) * 16;

  uint4 kreg0 = *(const uint4*)(kbase + kc8 * 8);
  uint4 kreg1 = *(const uint4*)(kbase + kc8 * 8 + 64);
  *(uint4*)(kt + krow * 256 + kswz0) = kreg0;
  *(uint4*)(kt + krow * 256 + kswz1) = kreg1;
  __syncthreads();   // kt(0), mk, zfin-zero visible

  float z[4] = {0.f, 0.f, 0.f, 0.f};
  const int tb = wq * 16 + colL;     // this wave's t-row within a chunk

  for (int c = 0; c < 32; ++c) {
    if (c < 31) {  // prefetch next chunk into regs (latency hides under compute)
      const unsigned short* kb2 = kbase + (size_t)(c + 1) * 64 * DD;
      kreg0 = *(const uint4*)(kb2 + kc8 * 8);
      kreg1 = *(const uint4*)(kb2 + kc8 * 8 + 64);
    }
    bf16x8 bb[4];
#pragma unroll
    for (int kk = 0; kk < 4; ++kk) {
      int phys = (kk * 4 + quad) ^ (tb & 7);
      bb[kk] = *(const bf16x8*)(kt + tb * 256 + phys * 16);
    }
    f32x4 acc = {0.f, 0.f, 0.f, 0.f};
    acc = __builtin_amdgcn_mfma_f32_16x16x32_bf16(qf[0], bb[0], acc, 0, 0, 0);
    acc = __builtin_amdgcn_mfma_f32_16x16x32_bf16(qf[1], bb[1], acc, 0, 0, 0);
    acc = __builtin_amdgcn_mfma_f32_16x16x32_bf16(qf[2], bb[2], acc, 0, 0, 0);
    acc = __builtin_amdgcn_mfma_f32_16x16x32_bf16(qf[3], bb[3], acc, 0, 0, 0);
    int tl = c * 64 + tb;
    int widx = tl >> 5, wb = tl & 31;
#pragma unroll
    for (int r = 0; r < 4; ++r) {
      int row_l = wr * 16 + quad * 4 + r;
      unsigned mw = mk[row_l * 65 + widx];
      float e = ((mw >> wb) & 1u) ? 0.f : __expf(fminf(acc[r], 80.f));
      z[r] += e;
      pt[row_l * 2048 + (tl ^ ((row_l & 7) << 3))] = f2bf(e);
    }
    if (c < 31) {
      __syncthreads();   // all waves done reading kt(c)
      *(uint4*)(kt + krow * 256 + kswz0) = kreg0;  // compiler waits vmcnt
      *(uint4*)(kt + krow * 256 + kswz1) = kreg1;
      __syncthreads();   // kt(c+1) visible
    }
  }

  // Z: reduce each lane's partial over the 16 t-lanes, then cross-wave in LDS
#pragma unroll
  for (int r = 0; r < 4; ++r) {
    float s = z[r];
    s += __shfl_xor(s, 1, 64);
    s += __shfl_xor(s, 2, 64);
    s += __shfl_xor(s, 4, 64);
    s += __shfl_xor(s, 8, 64);
    if (colL == 0) atomicAdd(&zfin[wr * 16 + quad * 4 + r], s);
  }
  __syncthreads();   // pt complete (all waves) + zfin complete
  if (tid < 32) zinvl[tid] = 1.0f / fmaxf(zfin[tid], 1e-30f);
  __syncthreads();

  // column sums: thread owns t0..t0+3; swizzle keeps 4-elem groups contiguous
  {
    const int t0 = tid * 4;
    float a0 = 0.f, a1 = 0.f, a2 = 0.f, a3 = 0.f;
#pragma unroll 8
    for (int r = 0; r < 32; ++r) {
      const unsigned short* pr = pt + r * 2048 + (t0 ^ ((r & 7) << 3));
      ushort4 pv = *(const ushort4*)pr;
      float zi = zinvl[r];
      a0 += bf2f(pv.x) * zi;
      a1 += bf2f(pv.y) * zi;
      a2 += bf2f(pv.z) * zi;
      a3 += bf2f(pv.w) * zi;
    }
    float* wrow = wg + (size_t)b * SS + t0;
    atomicAdd(&wrow[0], a0);
    atomicAdd(&wrow[1], a1);
    atomicAdd(&wrow[2], a2);
    atomicAdd(&wrow[3], a3);
  }
}

// ---------------- y partials: y[b][d] = sum_t wg[b][t] * V[b][t][d] ----------------
__global__ __launch_bounds__(256) void k_yv(const float* __restrict__ wgl,
                                            const unsigned short* __restrict__ vg,
                                            float* __restrict__ ygl) {
  const int tid = threadIdx.x;
  const int tc = blockIdx.x, b = blockIdx.y;
  const int d = tid & 127, half = tid >> 7;
  const int t0 = tc * 128 + half * 64;
  float p = 0.f;
  const float* wrow = wgl + (size_t)b * SS + t0;
  const unsigned short* vrow = vg + ((size_t)b * SS + t0) * DD + d;
#pragma unroll 8
  for (int t = 0; t < 64; ++t) p += wrow[t] * bf2f(vrow[(size_t)t * DD]);
  atomicAdd(&ygl[b * DD + d], p);
}

// ---------------- out = (y/S) @ Wl + bl  (fp32 out) ----------------
__global__ __launch_bounds__(256) void k_out(const float* __restrict__ ygl,
                                             const float* __restrict__ Wl,
                                             const float* __restrict__ bl,
                                             float* __restrict__ outp) {
  __shared__ float ys[DD];
  const int tid = threadIdx.x;
  const int b = blockIdx.x;
  if (tid < DD) ys[tid] = ygl[b * DD + tid] * (1.0f / 2048.0f);
  __syncthreads();
  for (int c = tid; c < CC; c += 256) {
    float a = bl[c];
#pragma unroll 16
    for (int dd = 0; dd < DD; ++dd) a += ys[dd] * Wl[dd * CC + c];
    outp[b * CC + c] = a;
  }
}

extern "C" void kernel_launch(void* const* d_in, const int* in_sizes, int n_in,
                              void* d_out, int out_size, void* d_ws, size_t ws_size,
                              hipStream_t stream) {
  const void* ptr[10];
  for (int i = 0; i < 10; ++i) ptr[i] = (i < n_in) ? d_in[i] : nullptr;
  if (n_in == 10) {  // size-based slot matching (no-op under dict order)
    const void *px = 0, *pm = 0, *pWl = 0, *pbl = 0;
    const void* pW[3] = {0, 0, 0};
    const void* pb[3] = {0, 0, 0};
    int nW = 0, nb = 0;
    for (int i = 0; i < 10; ++i) {
      int s = in_sizes[i];
      if (s == 16777216) px = d_in[i];
      else if (s == 67108864) pm = d_in[i];
      else if (s == 128000) pWl = d_in[i];
      else if (s == 1000) pbl = d_in[i];
      else if (s == 65536 && nW < 3) pW[nW++] = d_in[i];
      else if (s == 128 && nb < 3) pb[nb++] = d_in[i];
    }
    if (px && pm && pWl && pbl && nW == 3 && nb == 3) {
      ptr[0] = px; ptr[1] = pm;
      ptr[2] = pW[0]; ptr[3] = pb[0];
      ptr[4] = pW[1]; ptr[5] = pb[1];
      ptr[6] = pW[2]; ptr[7] = pb[2];
      ptr[8] = pWl; ptr[9] = pbl;
    }
  }
  char* ws = (char*)d_ws;
  if (ws_size < (size_t)WS_END) return;
  int* flags = (int*)ws;
  float* wg = (float*)(ws + WS_WG);
  float* zg = (float*)(ws + WS_ZG);
  float* yg = (float*)(ws + WS_YG);
  unsigned* pk = (unsigned*)(ws + WS_PK);
  unsigned short* q  = (unsigned short*)(ws + WS_Q);
  unsigned short* k  = (unsigned short*)(ws + WS_K);
  unsigned short* v  = (unsigned short*)(ws + WS_V);
  unsigned short* wt = (unsigned short*)(ws + WS_WT);

  k_wt<<<769, 256, 0, stream>>>((const float*)ptr[2], (const float*)ptr[4],
                                (const float*)ptr[6], wt,
                                (const unsigned*)ptr[1], flags, wg, zg, yg);
  k_pack<<<2048, 256, 0, stream>>>(ptr[1], flags, pk);
  k_proj<<<dim3(256, 3), 256, 0, stream>>>((const float*)ptr[0], wt,
                                           (const float*)ptr[3], (const float*)ptr[5],
                                           (const float*)ptr[7], q, k, v);
  k_fatt<<<dim3(64, 16), 512, 156032, stream>>>(q, k, pk, wg);
  k_yv<<<dim3(16, 16), 256, 0, stream>>>(wg, v, yg);
  k_out<<<16, 256, 0, stream>>>(yg, (const float*)ptr[8], (const float*)ptr[9],
                                (float*)d_out);
}

// Round 4
// 577.090 us; speedup vs baseline: 1.1009x; 1.0586x over previous
//
#include <hip/hip_runtime.h>
#include <stdint.h>

#define BB 16
#define SS 2048
#define FF 512
#define DD 128
#define CC 1000

typedef __attribute__((ext_vector_type(8))) short bf16x8;
typedef __attribute__((ext_vector_type(4))) float f32x4;

__device__ __forceinline__ unsigned short f2bf(float f) {
  unsigned x;
  __builtin_memcpy(&x, &f, 4);
  x = x + 0x7FFFu + ((x >> 16) & 1u);
  return (unsigned short)(x >> 16);
}
__device__ __forceinline__ float bf2f(unsigned short u) {
  unsigned x = ((unsigned)u) << 16;
  float f;
  __builtin_memcpy(&f, &x, 4);
  return f;
}
__device__ __forceinline__ unsigned pk2(float a, float b) {
  return (unsigned)f2bf(a) | ((unsigned)f2bf(b) << 16);
}

// ---- workspace layout (bytes) ----
#define WS_PK   0          // packed mask bits uint32 [B][S][64] (8 MB)
#define WS_Q    8388608    // bf16 [B][S][128], q pre-scaled by D^-0.5
#define WS_K    16777216
#define WS_V    25165824
#define WS_WT   33554432   // bf16 WT[3][128][512]
#define WS_WGP  33947648   // float wgp[B][64 rowgroups][2048] partial colsums (8 MB)
#define WS_END  42336256

// ---------------- prep: mask probe (per-block) + mask pack + W transpose ----------------
// grid 2048 x 256. Every block packs its 1/2048 share of the mask; blocks
// 0..767 additionally convert Wq/Wk/Wv fp32[512][128] -> bf16 WT[3][128][512].
__global__ __launch_bounds__(256) void k_prep(const void* __restrict__ mask,
                                              const float* __restrict__ Wq,
                                              const float* __restrict__ Wk,
                                              const float* __restrict__ Wv,
                                              unsigned short* __restrict__ wt,
                                              unsigned* __restrict__ pk) {
  __shared__ unsigned red;
  const int tid = threadIdx.x;
  if (tid == 0) red = 0;
  __syncthreads();
  {  // probe the global mask head (4 KB): int32 masks never set bits 8..31
    unsigned a = 0;
    const unsigned* m32 = (const unsigned*)mask;
#pragma unroll
    for (int j = 0; j < 4; ++j) a |= m32[tid * 4 + j] & 0xFFFFFF00u;
    if (a) atomicOr(&red, 1u);
  }
  __syncthreads();
  const bool isInt = (red == 0);

  const long long base = (long long)blockIdx.x * 32768;
  for (int it = 0; it < 128; ++it) {
    long long e = base + it * 256 + tid;
    int val;
    if (isInt) val = ((const int*)mask)[e];
    else       val = ((const unsigned char*)mask)[e];
    unsigned long long bal = __ballot(val != 0);
    if ((tid & 31) == 0)
      pk[e >> 5] = (unsigned)((tid & 63) ? (bal >> 32) : bal);
  }

  if (blockIdx.x < 768) {
    int idx = blockIdx.x * 256 + tid;
    int ty = idx >> 16;
    int o = idx & 65535;
    int d = o >> 9, f = o & 511;
    const float* W = ty == 0 ? Wq : (ty == 1 ? Wk : Wv);
    wt[idx] = f2bf(W[f * DD + d]);
  }
}

// ---------------- QKV projection (proven, unchanged) ----------------
__global__ __launch_bounds__(256) void k_proj(const float* __restrict__ xg,
                                              const unsigned short* __restrict__ wtg,
                                              const float* __restrict__ bq,
                                              const float* __restrict__ bk,
                                              const float* __restrict__ bv,
                                              unsigned short* __restrict__ qo,
                                              unsigned short* __restrict__ ko,
                                              unsigned short* __restrict__ vo) {
  __shared__ __align__(16) char lA[8192];
  __shared__ __align__(16) char lB[8192];
  const int tid = threadIdx.x;
  const int lane = tid & 63;
  const int wv = tid >> 6;
  const int colL = lane & 15, quad = lane >> 4;
  const int blk = blockIdx.x, ty = blockIdx.y;
  const float* bias = ty == 0 ? bq : (ty == 1 ? bk : bv);
  unsigned short* outp = ty == 0 ? qo : (ty == 1 ? ko : vo);
  const float scale = ty == 0 ? 0.08838834764831845f : 1.0f;
  const unsigned short* wbase = wtg + (size_t)ty * 65536;
  const int m0 = (wv & 1) * 64, n0 = (wv >> 1) * 64;

  f32x4 acc[4][4];
  const f32x4 z4 = {0.f, 0.f, 0.f, 0.f};
#pragma unroll
  for (int mi = 0; mi < 4; ++mi)
#pragma unroll
    for (int ni = 0; ni < 4; ++ni) acc[mi][ni] = z4;

  for (int ic = 0; ic < 16; ++ic) {
    const int k0 = ic * 32;
    uint4 va[2], vb[2];
#pragma unroll
    for (int rr = 0; rr < 2; ++rr) {
      int p = rr * 256 + tid;
      int row = p >> 2, c = p & 3;
      const float* xp = xg + (size_t)(blk * 128 + row) * FF + k0 + c * 8;
      float4 x0 = *(const float4*)xp;
      float4 x1 = *(const float4*)(xp + 4);
      va[rr].x = pk2(x0.x, x0.y); va[rr].y = pk2(x0.z, x0.w);
      va[rr].z = pk2(x1.x, x1.y); va[rr].w = pk2(x1.z, x1.w);
      vb[rr] = *(const uint4*)(wbase + (size_t)row * FF + k0 + c * 8);
    }
    __syncthreads();
#pragma unroll
    for (int rr = 0; rr < 2; ++rr) {
      int p = rr * 256 + tid;
      int row = p >> 2, c = p & 3;
      int phys = c ^ ((row >> 1) & 3);
      *(uint4*)(lA + row * 64 + phys * 16) = va[rr];
      *(uint4*)(lB + row * 64 + phys * 16) = vb[rr];
    }
    __syncthreads();
    bf16x8 af[4], bfr[4];
#pragma unroll
    for (int mi = 0; mi < 4; ++mi) {
      int ar = m0 + mi * 16 + colL;
      int phys = quad ^ ((ar >> 1) & 3);
      af[mi] = *(const bf16x8*)(lA + ar * 64 + phys * 16);
    }
#pragma unroll
    for (int ni = 0; ni < 4; ++ni) {
      int br = n0 + ni * 16 + colL;
      int phys = quad ^ ((br >> 1) & 3);
      bfr[ni] = *(const bf16x8*)(lB + br * 64 + phys * 16);
    }
#pragma unroll
    for (int mi = 0; mi < 4; ++mi)
#pragma unroll
      for (int ni = 0; ni < 4; ++ni)
        acc[mi][ni] = __builtin_amdgcn_mfma_f32_16x16x32_bf16(af[mi], bfr[ni], acc[mi][ni], 0, 0, 0);
  }
#pragma unroll
  for (int ni = 0; ni < 4; ++ni) {
    int col = n0 + ni * 16 + colL;
    float bval = bias[col];
#pragma unroll
    for (int mi = 0; mi < 4; ++mi) {
#pragma unroll
      for (int r = 0; r < 4; ++r) {
        int row = blk * 128 + m0 + mi * 16 + quad * 4 + r;
        float val = (acc[mi][ni][r] + bval) * scale;
        outp[(size_t)row * DD + col] = f2bf(val);
      }
    }
  }
}

// ---------------- fused attention: P kept entirely in LDS ----------------
// Identical to R3's proven kernel except the epilogue: column sums go to
// per-rowgroup partial buffer wgp[b][rg][t] with plain float4 stores
// (removes 2M contended global atomicAdds; k_tail reduces over rg).
__global__ __launch_bounds__(512, 2) void k_fatt(const unsigned short* __restrict__ qg,
                                                 const unsigned short* __restrict__ kg,
                                                 const unsigned* __restrict__ pk,
                                                 float* __restrict__ wgp) {
  extern __shared__ __align__(16) char smem[];
  unsigned short* pt = (unsigned short*)smem;          // [32][2048] bf16, 131072 B
  char* kt = smem + 131072;                            // [64][256 B] swizzled, 16384 B
  unsigned* mk = (unsigned*)(smem + 147456);           // [32][65] mask words, 8320 B
  float* zfin = (float*)(smem + 155776);               // [32]
  float* zinvl = (float*)(smem + 155904);              // [32]

  const int tid = threadIdx.x;
  const int lane = tid & 63, wv = tid >> 6;
  const int colL = lane & 15, quad = lane >> 4;
  const int wr = wv & 1, wq = wv >> 1;
  const int r0 = blockIdx.x * 32;
  const int b = blockIdx.y;

  for (int i = tid; i < 2048; i += 512) {
    int row = i >> 6, w = i & 63;
    mk[row * 65 + w] = pk[((size_t)b * SS + r0 + row) * 64 + w];
  }
  if (tid < 32) zfin[tid] = 0.f;

  bf16x8 qf[4];
  {
    int qrow = r0 + wr * 16 + colL;
    const unsigned short* qp = qg + ((size_t)b * SS + qrow) * DD + quad * 8;
#pragma unroll
    for (int kk = 0; kk < 4; ++kk) qf[kk] = *(const bf16x8*)(qp + kk * 32);
  }

  const int krow = tid >> 3, kc8 = tid & 7;
  const unsigned short* kbase = kg + ((size_t)b * SS + krow) * DD;
  const int kswz0 = (kc8 ^ (krow & 7)) * 16;
  const int kswz1 = ((kc8 + 8) ^ (krow & 7)) * 16;

  uint4 kreg0 = *(const uint4*)(kbase + kc8 * 8);
  uint4 kreg1 = *(const uint4*)(kbase + kc8 * 8 + 64);
  *(uint4*)(kt + krow * 256 + kswz0) = kreg0;
  *(uint4*)(kt + krow * 256 + kswz1) = kreg1;
  __syncthreads();

  float z[4] = {0.f, 0.f, 0.f, 0.f};
  const int tb = wq * 16 + colL;

  for (int c = 0; c < 32; ++c) {
    if (c < 31) {
      const unsigned short* kb2 = kbase + (size_t)(c + 1) * 64 * DD;
      kreg0 = *(const uint4*)(kb2 + kc8 * 8);
      kreg1 = *(const uint4*)(kb2 + kc8 * 8 + 64);
    }
    bf16x8 bb[4];
#pragma unroll
    for (int kk = 0; kk < 4; ++kk) {
      int phys = (kk * 4 + quad) ^ (tb & 7);
      bb[kk] = *(const bf16x8*)(kt + tb * 256 + phys * 16);
    }
    f32x4 acc = {0.f, 0.f, 0.f, 0.f};
    acc = __builtin_amdgcn_mfma_f32_16x16x32_bf16(qf[0], bb[0], acc, 0, 0, 0);
    acc = __builtin_amdgcn_mfma_f32_16x16x32_bf16(qf[1], bb[1], acc, 0, 0, 0);
    acc = __builtin_amdgcn_mfma_f32_16x16x32_bf16(qf[2], bb[2], acc, 0, 0, 0);
    acc = __builtin_amdgcn_mfma_f32_16x16x32_bf16(qf[3], bb[3], acc, 0, 0, 0);
    int tl = c * 64 + tb;
    int widx = tl >> 5, wb = tl & 31;
#pragma unroll
    for (int r = 0; r < 4; ++r) {
      int row_l = wr * 16 + quad * 4 + r;
      unsigned mw = mk[row_l * 65 + widx];
      float e = ((mw >> wb) & 1u) ? 0.f : __expf(fminf(acc[r], 80.f));
      z[r] += e;
      pt[row_l * 2048 + (tl ^ ((row_l & 7) << 3))] = f2bf(e);
    }
    if (c < 31) {
      __syncthreads();
      *(uint4*)(kt + krow * 256 + kswz0) = kreg0;
      *(uint4*)(kt + krow * 256 + kswz1) = kreg1;
      __syncthreads();
    }
  }

#pragma unroll
  for (int r = 0; r < 4; ++r) {
    float s = z[r];
    s += __shfl_xor(s, 1, 64);
    s += __shfl_xor(s, 2, 64);
    s += __shfl_xor(s, 4, 64);
    s += __shfl_xor(s, 8, 64);
    if (colL == 0) atomicAdd(&zfin[wr * 16 + quad * 4 + r], s);
  }
  __syncthreads();
  if (tid < 32) zinvl[tid] = 1.0f / fmaxf(zfin[tid], 1e-30f);
  __syncthreads();

  {
    const int t0 = tid * 4;
    float a0 = 0.f, a1 = 0.f, a2 = 0.f, a3 = 0.f;
#pragma unroll 8
    for (int r = 0; r < 32; ++r) {
      const unsigned short* pr = pt + r * 2048 + (t0 ^ ((r & 7) << 3));
      ushort4 pv = *(const ushort4*)pr;
      float zi = zinvl[r];
      a0 += bf2f(pv.x) * zi;
      a1 += bf2f(pv.y) * zi;
      a2 += bf2f(pv.z) * zi;
      a3 += bf2f(pv.w) * zi;
    }
    float4 o4;
    o4.x = a0; o4.y = a1; o4.z = a2; o4.w = a3;
    *(float4*)(wgp + ((size_t)b * 64 + blockIdx.x) * SS + t0) = o4;
  }
}

// ---------------- tail: wgp-reduce, y = w.V, out = (y/S)@Wl + bl ----------------
// One block per batch, 1024 threads.
__global__ __launch_bounds__(1024) void k_tail(const float* __restrict__ wgp,
                                               const unsigned short* __restrict__ vg,
                                               const float* __restrict__ Wl,
                                               const float* __restrict__ bl,
                                               float* __restrict__ outp) {
  __shared__ float ws2[2048];
  __shared__ float yp[8][128];
  __shared__ float ys[128];
  const int tid = threadIdx.x;
  const int b = blockIdx.x;

  {  // reduce 64 rowgroup partials -> wg row
    float s0 = 0.f, s1 = 0.f;
    const float* wp = wgp + ((size_t)b * 64) * SS + tid * 2;
#pragma unroll 8
    for (int rg = 0; rg < 64; ++rg) {
      s0 += wp[rg * SS];
      s1 += wp[rg * SS + 1];
    }
    ws2[tid * 2] = s0;
    ws2[tid * 2 + 1] = s1;
  }
  __syncthreads();

  {  // y[d] = sum_t ws2[t] * V[b][t][d]
    const int d = tid & 127, tg = tid >> 7;
    const int t0 = tg * 256;
    float p = 0.f;
    const unsigned short* vr = vg + ((size_t)b * SS + t0) * DD + d;
#pragma unroll 8
    for (int t = 0; t < 256; ++t) p += ws2[t0 + t] * bf2f(vr[(size_t)t * DD]);
    yp[tg][d] = p;
  }
  __syncthreads();
  if (tid < 128) {
    float a = 0.f;
#pragma unroll
    for (int g = 0; g < 8; ++g) a += yp[g][tid];
    ys[tid] = a * (1.0f / 2048.0f);
  }
  __syncthreads();

  if (tid < CC) {
    float a = bl[tid];
#pragma unroll 16
    for (int dd = 0; dd < DD; ++dd) a += ys[dd] * Wl[dd * CC + tid];
    outp[b * CC + tid] = a;
  }
}

extern "C" void kernel_launch(void* const* d_in, const int* in_sizes, int n_in,
                              void* d_out, int out_size, void* d_ws, size_t ws_size,
                              hipStream_t stream) {
  const void* ptr[10];
  for (int i = 0; i < 10; ++i) ptr[i] = (i < n_in) ? d_in[i] : nullptr;
  if (n_in == 10) {  // size-based slot matching (no-op under dict order)
    const void *px = 0, *pm = 0, *pWl = 0, *pbl = 0;
    const void* pW[3] = {0, 0, 0};
    const void* pb[3] = {0, 0, 0};
    int nW = 0, nb = 0;
    for (int i = 0; i < 10; ++i) {
      int s = in_sizes[i];
      if (s == 16777216) px = d_in[i];
      else if (s == 67108864) pm = d_in[i];
      else if (s == 128000) pWl = d_in[i];
      else if (s == 1000) pbl = d_in[i];
      else if (s == 65536 && nW < 3) pW[nW++] = d_in[i];
      else if (s == 128 && nb < 3) pb[nb++] = d_in[i];
    }
    if (px && pm && pWl && pbl && nW == 3 && nb == 3) {
      ptr[0] = px; ptr[1] = pm;
      ptr[2] = pW[0]; ptr[3] = pb[0];
      ptr[4] = pW[1]; ptr[5] = pb[1];
      ptr[6] = pW[2]; ptr[7] = pb[2];
      ptr[8] = pWl; ptr[9] = pbl;
    }
  }
  char* ws = (char*)d_ws;
  if (ws_size < (size_t)WS_END) return;
  unsigned* pk = (unsigned*)(ws + WS_PK);
  unsigned short* q  = (unsigned short*)(ws + WS_Q);
  unsigned short* k  = (unsigned short*)(ws + WS_K);
  unsigned short* v  = (unsigned short*)(ws + WS_V);
  unsigned short* wt = (unsigned short*)(ws + WS_WT);
  float* wgp = (float*)(ws + WS_WGP);

  k_prep<<<2048, 256, 0, stream>>>(ptr[1], (const float*)ptr[2], (const float*)ptr[4],
                                   (const float*)ptr[6], wt, pk);
  k_proj<<<dim3(256, 3), 256, 0, stream>>>((const float*)ptr[0], wt,
                                           (const float*)ptr[3], (const float*)ptr[5],
                                           (const float*)ptr[7], q, k, v);
  k_fatt<<<dim3(64, 16), 512, 156032, stream>>>(q, k, pk, wgp);
  k_tail<<<16, 1024, 0, stream>>>(wgp, v, (const float*)ptr[8], (const float*)ptr[9],
                                  (float*)d_out);
}